// Round 13
// baseline (71.632 us; speedup 1.0000x reference)
//
#include <hip/hip_runtime.h>

#define B_ 4
#define C_ 128
#define N_ 4096
#define LOG2E 1.44269504088896340736f
#define KB_PER_B (C_ * N_ * 2)          // 1 MiB per batch for kQ / vQ

typedef __bf16 bf16x8 __attribute__((ext_vector_type(8)));
typedef __bf16 bf16x4 __attribute__((ext_vector_type(4)));
typedef float  f32x16 __attribute__((ext_vector_type(16)));
typedef int    i32x4  __attribute__((ext_vector_type(4)));

// ---------------- projection: q/k/v = W @ x + b (1x1 conv) -------------
// qT [B][N][C] bf16 (q scaled by log2e).
// kQ [B][tile32][plane p=2ch+h: 512B][key 32][16B]  : lane frag = one load
//    plane p holds K[key][c = 8p .. 8p+7]
// vQ [B][tile32][plane u=cb*4+2m+hv: 512B][row c&31][16B, M2 key order]
//    element e of plane (cb,m,hv) row r = V[cb*32+r][16m+4hv+(e&3)+8(e>>2)]
__global__ __launch_bounds__(256) void proj_kernel(
    const float* __restrict__ x,
    const float* __restrict__ Wq, const float* __restrict__ bq,
    const float* __restrict__ Wk, const float* __restrict__ bk,
    const float* __restrict__ Wv, const float* __restrict__ bv,
    unsigned short* __restrict__ qT, char* __restrict__ kQ,
    char* __restrict__ vQ)
{
    __shared__ __align__(16) char wlds[32768];   // W bf16, swizzled rows (256B)

    const int tid  = threadIdx.x;
    const int wave = tid >> 6;
    const int lane = tid & 63;
    const int col  = lane & 31;
    const int h    = lane >> 5;

    const int jw  = blockIdx.x * 4 + wave;   // 0..1535 = mat*512 + b*128 + nb
    const int mat = jw >> 9;                 // uniform per WG
    const int rem = jw & 511;
    const int b   = rem >> 7;
    const int nb  = rem & 127;               // 32-key tile index
    const int n   = nb * 32 + col;

    const float* W    = (mat == 0) ? Wq : (mat == 1) ? Wk : Wv;
    const float* bias = (mat == 0) ? bq : (mat == 1) ? bk : bv;
    const float  scale = (mat == 0) ? LOG2E : 1.0f;

    #pragma unroll
    for (int k = 0; k < 16; ++k) {
        const int q = tid + k * 256;          // quad index, 4 floats each
        const int o = q >> 5;                 // W row (output channel)
        const int g = q & 31;                 // 8B granule within row
        float4 w = *((const float4*)W + q);
        bf16x4 d;
        d[0] = (__bf16)(w.x * scale); d[1] = (__bf16)(w.y * scale);
        d[2] = (__bf16)(w.z * scale); d[3] = (__bf16)(w.w * scale);
        *(bf16x4*)(wlds + o * 256 + ((((g >> 1) ^ (o & 15)) << 4) | ((g & 1) * 8))) = d;
    }
    __syncthreads();

    bf16x8 xf[8];
    const float* xcol = x + (size_t)b * C_ * N_ + n;
    #pragma unroll
    for (int ch = 0; ch < 8; ++ch) {
        const int c0 = ch * 16 + 8 * h;
        bf16x8 v;
        #pragma unroll
        for (int e = 0; e < 8; ++e) v[e] = (__bf16)xcol[(size_t)(c0 + e) * N_];
        xf[ch] = v;
    }

    f32x16 acc[4];
    #pragma unroll
    for (int ob = 0; ob < 4; ++ob)
        #pragma unroll
        for (int rr = 0; rr < 16; ++rr) acc[ob][rr] = 0.0f;

    #pragma unroll
    for (int ch = 0; ch < 8; ++ch) {
        #pragma unroll
        for (int ob = 0; ob < 4; ++ob) {
            const char* wrow = wlds + (ob * 32 + col) * 256;
            bf16x8 wf = __builtin_bit_cast(bf16x8,
                *(const i32x4*)(wrow + (((ch * 2 + h) ^ (col & 15)) << 4)));
            acc[ob] = __builtin_amdgcn_mfma_f32_32x32x16_bf16(
                wf, xf[ch], acc[ob], 0, 0, 0);
        }
    }

    if (mat == 0) {
        unsigned short* dst = qT + (size_t)(b * N_ + n) * C_;
        #pragma unroll
        for (int ob = 0; ob < 4; ++ob) {
            #pragma unroll
            for (int qd = 0; qd < 4; ++qd) {
                const int obase = ob * 32 + 8 * qd + 4 * h;
                bf16x4 d;
                d[0] = (__bf16)(acc[ob][4 * qd + 0] + bias[obase + 0] * scale);
                d[1] = (__bf16)(acc[ob][4 * qd + 1] + bias[obase + 1] * scale);
                d[2] = (__bf16)(acc[ob][4 * qd + 2] + bias[obase + 2] * scale);
                d[3] = (__bf16)(acc[ob][4 * qd + 3] + bias[obase + 3] * scale);
                *(bf16x4*)(dst + obase) = d;
            }
        }
    } else if (mat == 1) {
        // plane p = c>>3 (= ob*4+qd for both h); byte = p*512 + key*16 + 8h
        char* dst = kQ + (size_t)b * KB_PER_B + (size_t)nb * 8192 + col * 16 + 8 * h;
        #pragma unroll
        for (int ob = 0; ob < 4; ++ob) {
            #pragma unroll
            for (int qd = 0; qd < 4; ++qd) {
                const int obase = ob * 32 + 8 * qd + 4 * h;
                bf16x4 d;
                d[0] = (__bf16)(acc[ob][4 * qd + 0] + bias[obase + 0]);
                d[1] = (__bf16)(acc[ob][4 * qd + 1] + bias[obase + 1]);
                d[2] = (__bf16)(acc[ob][4 * qd + 2] + bias[obase + 2]);
                d[3] = (__bf16)(acc[ob][4 * qd + 3] + bias[obase + 3]);
                *(bf16x4*)(dst + (ob * 4 + qd) * 512) = d;
            }
        }
    } else {
        char* dst = vQ + (size_t)b * KB_PER_B + (size_t)nb * 8192;
        const int m  = (col >> 4) & 1;
        const int w16 = col & 15;
        const int hv = (w16 >> 2) & 1;
        const int e  = (w16 & 3) | ((w16 >> 3) << 2);   // M2 element index
        #pragma unroll
        for (int ob = 0; ob < 4; ++ob) {
            #pragma unroll
            for (int rr = 0; rr < 16; ++rr) {
                const int o = ob * 32 + (rr & 3) + 8 * (rr >> 2) + 4 * h;
                *(unsigned short*)(dst + (ob * 4 + m * 2 + hv) * 512
                                       + (o & 31) * 16 + e * 2) =
                    __builtin_bit_cast(unsigned short,
                                       (__bf16)(acc[ob][rr] + bias[o]));
            }
        }
    }
}

// ---------------- flash attention over N/NS keys per WG ----------------
// grid = B * (N/128) * NS WGs x 256 thr. 4 independent waves (32 q each)
// stream K/V tiles DIRECTLY global->registers. NO LDS, NO barriers.
// FIXED-SHIFT softmax: p = exp2(e) (shift-invariant; merged exactly later).
template<int NS>
__global__ __launch_bounds__(256, 2) void attn_kernel(
    const unsigned short* __restrict__ qT,
    const char* __restrict__ kQ,
    const char* __restrict__ vQ,
    unsigned short* __restrict__ pO,  // [NS][B][C][N] bf16 (un-normalized)
    float* __restrict__ lG)           // [NS][B][N] denominators
{
    const int tid  = threadIdx.x;
    const int w    = tid >> 6;
    const int lane = tid & 63;
    const int l31  = lane & 31;
    const int h    = lane >> 5;

    const int orig = blockIdx.x;
    const int b    = (orig & 7) >> 1;                  // XCD-pair per batch
    const int idx  = ((orig >> 3) << 1) | (orig & 1);
    const int part = idx % NS;
    const int qg   = idx / NS;                         // 0..31
    const int i0   = qg * 128 + w * 32;

    const int NT = N_ / (NS * 32);                     // 32-key tiles per wave
    const char* kq0 = kQ + (size_t)b * KB_PER_B + (size_t)(part * NT) * 8192;
    const char* vq0 = vQ + (size_t)b * KB_PER_B + (size_t)(part * NT) * 8192;
    const int lbase = h * 512 + l31 * 16;              // per-lane frag offset

    // Q fragments: element e of chunk ch <-> c = ch*16 + 8h + e
    bf16x8 qf[8];
    {
        const unsigned short* qrow = qT + (size_t)(b * N_ + i0 + l31) * C_;
        #pragma unroll
        for (int ch = 0; ch < 8; ++ch)
            qf[ch] = __builtin_bit_cast(bf16x8, *(const i32x4*)(qrow + ch * 16 + 8 * h));
    }

    f32x16 accO[4];
    #pragma unroll
    for (int cb = 0; cb < 4; ++cb)
        #pragma unroll
        for (int rr = 0; rr < 16; ++rr) accO[cb][rr] = 0.0f;
    float l_run = 0.0f;

    i32x4 kreg[8], vreg[8];
    auto loadK = [&](int t) {
        const char* ka = kq0 + (size_t)t * 8192 + lbase;   // plane 2ch+h
        #pragma unroll
        for (int ch = 0; ch < 8; ++ch)
            kreg[ch] = *(const i32x4*)(ka + ch * 1024);
    };
    auto loadV = [&](int t) {
        const char* va = vq0 + (size_t)t * 8192 + lbase;   // plane cb*4+2m+h
        #pragma unroll
        for (int u = 0; u < 8; ++u)
            vreg[u] = *(const i32x4*)(va + u * 1024);
    };

    loadK(0);
    loadV(0);

    #pragma unroll 1
    for (int t = 0; t < NT; ++t) {
        // ---- E^T[j][i] = sum_c K[c,j] Q[c,i] (keys j = 0..31 of tile) ----
        f32x16 e;
        #pragma unroll
        for (int rr = 0; rr < 16; ++rr) e[rr] = 0.0f;
        __builtin_amdgcn_s_setprio(1);
        #pragma unroll
        for (int ch = 0; ch < 8; ++ch)
            e = __builtin_amdgcn_mfma_f32_32x32x16_bf16(
                __builtin_bit_cast(bf16x8, kreg[ch]), qf[ch], e, 0, 0, 0);
        __builtin_amdgcn_s_setprio(0);

        if (t + 1 < NT) loadK(t + 1);      // prefetch next K (WAR on kreg)

        // ---- fixed-shift softmax numerators + denominator ----
        float lsum = 0.0f;
        #pragma unroll
        for (int rr = 0; rr < 16; ++rr) { e[rr] = exp2f(e[rr]); lsum += e[rr]; }
        l_run += lsum;

        // pack P: frag m element ee <-> key 16m + 4h + (ee&3) + 8*(ee>>2)
        bf16x8 pf[2];
        #pragma unroll
        for (int m = 0; m < 2; ++m) {
            bf16x8 p;
            #pragma unroll
            for (int ee = 0; ee < 8; ++ee) p[ee] = (__bf16)e[m * 8 + ee];
            pf[m] = p;
        }

        // ---- accO[c][i] += sum_j V[c,j] P[j,i] ----
        __builtin_amdgcn_s_setprio(1);
        #pragma unroll
        for (int cb = 0; cb < 4; ++cb) {
            accO[cb] = __builtin_amdgcn_mfma_f32_32x32x16_bf16(
                __builtin_bit_cast(bf16x8, vreg[cb * 2 + 0]), pf[0], accO[cb], 0, 0, 0);
            accO[cb] = __builtin_amdgcn_mfma_f32_32x32x16_bf16(
                __builtin_bit_cast(bf16x8, vreg[cb * 2 + 1]), pf[1], accO[cb], 0, 0, 0);
        }
        __builtin_amdgcn_s_setprio(0);

        if (t + 1 < NT) loadV(t + 1);      // prefetch next V (WAR on vreg)
    }

    // ---- epilogue: un-normalized partial O (bf16) + denominator ----
    l_run += __shfl_xor(l_run, 32, 64);    // combine the two h key-halves
    if (h == 0)
        lG[((size_t)part * B_ + b) * N_ + i0 + l31] = l_run;

    unsigned short* pOq = pO + ((size_t)part * B_ + b) * C_ * N_;
    #pragma unroll
    for (int cb = 0; cb < 4; ++cb) {
        #pragma unroll
        for (int rr = 0; rr < 16; ++rr) {
            const int c = cb * 32 + (rr & 3) + 8 * (rr >> 2) + 4 * h;
            pOq[(size_t)c * N_ + i0 + l31] =
                __builtin_bit_cast(unsigned short, (__bf16)accO[cb][rr]);
        }
    }
}

// ---------------- merge NS key-range partials + residual ----------------
// Same fixed shift everywhere => merge is a plain sum.
template<int NS>
__global__ __launch_bounds__(256) void merge_kernel(
    const float* __restrict__ x,
    const unsigned short* __restrict__ pO,   // [NS][B][C][N] bf16
    const float* __restrict__ lG,            // [NS][B][N]
    float* __restrict__ out)
{
    const int idx = blockIdx.x * 256 + threadIdx.x;   // over B*C*N/4
    const int nq  = idx & (N_ / 4 - 1);
    const int bc  = idx >> 10;                        // b*C + c
    const int b   = bc >> 7;
    const size_t off = (size_t)bc * N_ + nq * 4;

    float4 xv = *(const float4*)(x + off);

    float num[4] = {0, 0, 0, 0}, den[4] = {0, 0, 0, 0};
    #pragma unroll
    for (int q = 0; q < NS; ++q) {
        bf16x4 r = *(const bf16x4*)(pO + (size_t)q * B_ * C_ * N_ + off);
        const float* lp = lG + ((size_t)q * B_ + b) * N_ + nq * 4;
        #pragma unroll
        for (int j = 0; j < 4; ++j) {
            num[j] += (float)r[j];
            den[j] += lp[j];
        }
    }
    float4 ov;
    ov.x = xv.x + num[0] / den[0];
    ov.y = xv.y + num[1] / den[1];
    ov.z = xv.z + num[2] / den[2];
    ov.w = xv.w + num[3] / den[3];
    *(float4*)(out + off) = ov;
}

extern "C" void kernel_launch(void* const* d_in, const int* in_sizes, int n_in,
                              void* d_out, int out_size, void* d_ws, size_t ws_size,
                              hipStream_t stream)
{
    const float* x  = (const float*)d_in[0];
    const float* Wq = (const float*)d_in[1];
    const float* bq = (const float*)d_in[2];
    const float* Wk = (const float*)d_in[3];
    const float* bk = (const float*)d_in[4];
    const float* Wv = (const float*)d_in[5];
    const float* bv = (const float*)d_in[6];
    float* out = (float*)d_out;

    unsigned short* qT = (unsigned short*)d_ws;              // 4 MiB
    char* kQ = (char*)(qT + (size_t)B_ * N_ * C_);           // 4 MiB
    char* vQ = kQ + (size_t)B_ * KB_PER_B;                   // 4 MiB
    unsigned short* pO = (unsigned short*)(vQ + (size_t)B_ * KB_PER_B);

    const size_t slotO = (size_t)B_ * C_ * N_;               // bf16 elems / slot
    const size_t slotL = (size_t)B_ * N_;                    // floats / slot
    const size_t base  = 3ull * B_ * N_ * C_ * 2;
    const size_t need4 = base + 4 * (slotO * 2 + slotL * 4);
    const int nMerge = (B_ * C_ * N_ / 4) / 256;

    proj_kernel<<<384, 256, 0, stream>>>(x, Wq, bq, Wk, bk, Wv, bv, qT, kQ, vQ);

    if (ws_size >= need4) {
        float* lG = (float*)(pO + 4 * slotO);
        attn_kernel<4><<<B_ * (N_ / 128) * 4, 256, 0, stream>>>(qT, kQ, vQ, pO, lG);
        merge_kernel<4><<<nMerge, 256, 0, stream>>>(x, pO, lG, out);
    } else {
        float* lG = (float*)(pO + 2 * slotO);
        attn_kernel<2><<<B_ * (N_ / 128) * 2, 256, 0, stream>>>(qT, kQ, vQ, pO, lG);
        merge_kernel<2><<<nMerge, 256, 0, stream>>>(x, pO, lG, out);
    }
}

// Round 14
// 71.206 us; speedup vs baseline: 1.0060x; 1.0060x over previous
//
#include <hip/hip_runtime.h>

#define B_ 4
#define C_ 128
#define N_ 4096
#define LOG2E 1.44269504088896340736f
#define KB_PER_B (C_ * N_ * 2)          // 1 MiB per batch for kQ / vQ

typedef __bf16 bf16x8 __attribute__((ext_vector_type(8)));
typedef __bf16 bf16x4 __attribute__((ext_vector_type(4)));
typedef float  f32x16 __attribute__((ext_vector_type(16)));
typedef int    i32x4  __attribute__((ext_vector_type(4)));

// ---------------- projection: q/k/v = W @ x + b (1x1 conv) -------------
// qT [B][N][C] bf16 (q scaled by log2e).
// kQ [B][tile32][plane p=2ch+h: 512B][key 32][16B]  : lane frag = one load
//    plane p holds K[key][c = 8p .. 8p+7]
// vQ [B][tile32][plane u=cb*4+2m+hv: 512B][row c&31][16B, M2 key order]
//    element e of plane (cb,m,hv) row r = V[cb*32+r][16m+4hv+(e&3)+8(e>>2)]
__global__ __launch_bounds__(256) void proj_kernel(
    const float* __restrict__ x,
    const float* __restrict__ Wq, const float* __restrict__ bq,
    const float* __restrict__ Wk, const float* __restrict__ bk,
    const float* __restrict__ Wv, const float* __restrict__ bv,
    unsigned short* __restrict__ qT, char* __restrict__ kQ,
    char* __restrict__ vQ)
{
    __shared__ __align__(16) char wlds[32768];   // W bf16, swizzled rows (256B)

    const int tid  = threadIdx.x;
    const int wave = tid >> 6;
    const int lane = tid & 63;
    const int col  = lane & 31;
    const int h    = lane >> 5;

    const int jw  = blockIdx.x * 4 + wave;   // 0..1535 = mat*512 + b*128 + nb
    const int mat = jw >> 9;                 // uniform per WG
    const int rem = jw & 511;
    const int b   = rem >> 7;
    const int nb  = rem & 127;               // 32-key tile index
    const int n   = nb * 32 + col;

    const float* W    = (mat == 0) ? Wq : (mat == 1) ? Wk : Wv;
    const float* bias = (mat == 0) ? bq : (mat == 1) ? bk : bv;
    const float  scale = (mat == 0) ? LOG2E : 1.0f;

    #pragma unroll
    for (int k = 0; k < 16; ++k) {
        const int q = tid + k * 256;          // quad index, 4 floats each
        const int o = q >> 5;                 // W row (output channel)
        const int g = q & 31;                 // 8B granule within row
        float4 w = *((const float4*)W + q);
        bf16x4 d;
        d[0] = (__bf16)(w.x * scale); d[1] = (__bf16)(w.y * scale);
        d[2] = (__bf16)(w.z * scale); d[3] = (__bf16)(w.w * scale);
        *(bf16x4*)(wlds + o * 256 + ((((g >> 1) ^ (o & 15)) << 4) | ((g & 1) * 8))) = d;
    }
    __syncthreads();

    bf16x8 xf[8];
    const float* xcol = x + (size_t)b * C_ * N_ + n;
    #pragma unroll
    for (int ch = 0; ch < 8; ++ch) {
        const int c0 = ch * 16 + 8 * h;
        bf16x8 v;
        #pragma unroll
        for (int e = 0; e < 8; ++e) v[e] = (__bf16)xcol[(size_t)(c0 + e) * N_];
        xf[ch] = v;
    }

    f32x16 acc[4];
    #pragma unroll
    for (int ob = 0; ob < 4; ++ob)
        #pragma unroll
        for (int rr = 0; rr < 16; ++rr) acc[ob][rr] = 0.0f;

    #pragma unroll
    for (int ch = 0; ch < 8; ++ch) {
        #pragma unroll
        for (int ob = 0; ob < 4; ++ob) {
            const char* wrow = wlds + (ob * 32 + col) * 256;
            bf16x8 wf = __builtin_bit_cast(bf16x8,
                *(const i32x4*)(wrow + (((ch * 2 + h) ^ (col & 15)) << 4)));
            acc[ob] = __builtin_amdgcn_mfma_f32_32x32x16_bf16(
                wf, xf[ch], acc[ob], 0, 0, 0);
        }
    }

    if (mat == 0) {
        unsigned short* dst = qT + (size_t)(b * N_ + n) * C_;
        #pragma unroll
        for (int ob = 0; ob < 4; ++ob) {
            #pragma unroll
            for (int qd = 0; qd < 4; ++qd) {
                const int obase = ob * 32 + 8 * qd + 4 * h;
                bf16x4 d;
                d[0] = (__bf16)(acc[ob][4 * qd + 0] + bias[obase + 0] * scale);
                d[1] = (__bf16)(acc[ob][4 * qd + 1] + bias[obase + 1] * scale);
                d[2] = (__bf16)(acc[ob][4 * qd + 2] + bias[obase + 2] * scale);
                d[3] = (__bf16)(acc[ob][4 * qd + 3] + bias[obase + 3] * scale);
                *(bf16x4*)(dst + obase) = d;
            }
        }
    } else if (mat == 1) {
        // plane p = c>>3 (= ob*4+qd for both h); byte = p*512 + key*16 + 8h
        char* dst = kQ + (size_t)b * KB_PER_B + (size_t)nb * 8192 + col * 16 + 8 * h;
        #pragma unroll
        for (int ob = 0; ob < 4; ++ob) {
            #pragma unroll
            for (int qd = 0; qd < 4; ++qd) {
                const int obase = ob * 32 + 8 * qd + 4 * h;
                bf16x4 d;
                d[0] = (__bf16)(acc[ob][4 * qd + 0] + bias[obase + 0]);
                d[1] = (__bf16)(acc[ob][4 * qd + 1] + bias[obase + 1]);
                d[2] = (__bf16)(acc[ob][4 * qd + 2] + bias[obase + 2]);
                d[3] = (__bf16)(acc[ob][4 * qd + 3] + bias[obase + 3]);
                *(bf16x4*)(dst + (ob * 4 + qd) * 512) = d;
            }
        }
    } else {
        char* dst = vQ + (size_t)b * KB_PER_B + (size_t)nb * 8192;
        const int m  = (col >> 4) & 1;
        const int w16 = col & 15;
        const int hv = (w16 >> 2) & 1;
        const int e  = (w16 & 3) | ((w16 >> 3) << 2);   // M2 element index
        #pragma unroll
        for (int ob = 0; ob < 4; ++ob) {
            #pragma unroll
            for (int rr = 0; rr < 16; ++rr) {
                const int o = ob * 32 + (rr & 3) + 8 * (rr >> 2) + 4 * h;
                *(unsigned short*)(dst + (ob * 4 + m * 2 + hv) * 512
                                       + (o & 31) * 16 + e * 2) =
                    __builtin_bit_cast(unsigned short,
                                       (__bf16)(acc[ob][rr] + bias[o]));
            }
        }
    }
}

// ---------------- flash attention over N/NS keys per WG ----------------
// grid = B * (N/128) * NS WGs x 256 thr. 4 independent waves (32 q each)
// stream K/V tiles DIRECTLY global->registers. NO LDS, NO barriers.
// FIXED-SHIFT softmax: p = exp2(e) (shift-invariant; merged exactly later).
template<int NS>
__global__ __launch_bounds__(256, 2) void attn_kernel(
    const unsigned short* __restrict__ qT,
    const char* __restrict__ kQ,
    const char* __restrict__ vQ,
    unsigned short* __restrict__ pO,  // [NS][B][C][N] bf16 (un-normalized)
    float* __restrict__ lG)           // [NS][B][N] denominators
{
    const int tid  = threadIdx.x;
    const int w    = tid >> 6;
    const int lane = tid & 63;
    const int l31  = lane & 31;
    const int h    = lane >> 5;

    const int orig = blockIdx.x;
    const int b    = (orig & 7) >> 1;                  // XCD-pair per batch
    const int idx  = ((orig >> 3) << 1) | (orig & 1);
    const int part = idx % NS;
    const int qg   = idx / NS;                         // 0..31
    const int i0   = qg * 128 + w * 32;

    const int NT = N_ / (NS * 32);                     // 32-key tiles per wave
    const char* kq0 = kQ + (size_t)b * KB_PER_B + (size_t)(part * NT) * 8192;
    const char* vq0 = vQ + (size_t)b * KB_PER_B + (size_t)(part * NT) * 8192;
    const int lbase = h * 512 + l31 * 16;              // per-lane frag offset

    // Q fragments: element e of chunk ch <-> c = ch*16 + 8h + e
    bf16x8 qf[8];
    {
        const unsigned short* qrow = qT + (size_t)(b * N_ + i0 + l31) * C_;
        #pragma unroll
        for (int ch = 0; ch < 8; ++ch)
            qf[ch] = __builtin_bit_cast(bf16x8, *(const i32x4*)(qrow + ch * 16 + 8 * h));
    }

    f32x16 accO[4];
    #pragma unroll
    for (int cb = 0; cb < 4; ++cb)
        #pragma unroll
        for (int rr = 0; rr < 16; ++rr) accO[cb][rr] = 0.0f;
    float l_run = 0.0f;

    i32x4 kreg[8], vreg[8];
    auto loadK = [&](int t) {
        const char* ka = kq0 + (size_t)t * 8192 + lbase;   // plane 2ch+h
        #pragma unroll
        for (int ch = 0; ch < 8; ++ch)
            kreg[ch] = *(const i32x4*)(ka + ch * 1024);
    };
    auto loadV = [&](int t) {
        const char* va = vq0 + (size_t)t * 8192 + lbase;   // plane cb*4+2m+h
        #pragma unroll
        for (int u = 0; u < 8; ++u)
            vreg[u] = *(const i32x4*)(va + u * 1024);
    };

    loadK(0);
    loadV(0);

    #pragma unroll 1
    for (int t = 0; t < NT; ++t) {
        // ---- E^T[j][i] = sum_c K[c,j] Q[c,i] (keys j = 0..31 of tile) ----
        f32x16 e;
        #pragma unroll
        for (int rr = 0; rr < 16; ++rr) e[rr] = 0.0f;
        __builtin_amdgcn_s_setprio(1);
        #pragma unroll
        for (int ch = 0; ch < 8; ++ch)
            e = __builtin_amdgcn_mfma_f32_32x32x16_bf16(
                __builtin_bit_cast(bf16x8, kreg[ch]), qf[ch], e, 0, 0, 0);
        __builtin_amdgcn_s_setprio(0);

        if (t + 1 < NT) loadK(t + 1);      // prefetch next K (WAR on kreg)

        // ---- fixed-shift softmax numerators + denominator ----
        float lsum = 0.0f;
        #pragma unroll
        for (int rr = 0; rr < 16; ++rr) { e[rr] = exp2f(e[rr]); lsum += e[rr]; }
        l_run += lsum;

        // pack P: frag m element ee <-> key 16m + 4h + (ee&3) + 8*(ee>>2)
        bf16x8 pf[2];
        #pragma unroll
        for (int m = 0; m < 2; ++m) {
            bf16x8 p;
            #pragma unroll
            for (int ee = 0; ee < 8; ++ee) p[ee] = (__bf16)e[m * 8 + ee];
            pf[m] = p;
        }

        // ---- accO[c][i] += sum_j V[c,j] P[j,i] ----
        __builtin_amdgcn_s_setprio(1);
        #pragma unroll
        for (int cb = 0; cb < 4; ++cb) {
            accO[cb] = __builtin_amdgcn_mfma_f32_32x32x16_bf16(
                __builtin_bit_cast(bf16x8, vreg[cb * 2 + 0]), pf[0], accO[cb], 0, 0, 0);
            accO[cb] = __builtin_amdgcn_mfma_f32_32x32x16_bf16(
                __builtin_bit_cast(bf16x8, vreg[cb * 2 + 1]), pf[1], accO[cb], 0, 0, 0);
        }
        __builtin_amdgcn_s_setprio(0);

        if (t + 1 < NT) loadV(t + 1);      // prefetch next V (WAR on vreg)
    }

    // ---- epilogue: un-normalized partial O (bf16) + denominator ----
    l_run += __shfl_xor(l_run, 32, 64);    // combine the two h key-halves
    if (h == 0)
        lG[((size_t)part * B_ + b) * N_ + i0 + l31] = l_run;

    unsigned short* pOq = pO + ((size_t)part * B_ + b) * C_ * N_;
    #pragma unroll
    for (int cb = 0; cb < 4; ++cb) {
        #pragma unroll
        for (int rr = 0; rr < 16; ++rr) {
            const int c = cb * 32 + (rr & 3) + 8 * (rr >> 2) + 4 * h;
            pOq[(size_t)c * N_ + i0 + l31] =
                __builtin_bit_cast(unsigned short, (__bf16)accO[cb][rr]);
        }
    }
}

// ---------------- merge NS key-range partials + residual ----------------
// Same fixed shift everywhere => merge is a plain sum.
template<int NS>
__global__ __launch_bounds__(256) void merge_kernel(
    const float* __restrict__ x,
    const unsigned short* __restrict__ pO,   // [NS][B][C][N] bf16
    const float* __restrict__ lG,            // [NS][B][N]
    float* __restrict__ out)
{
    const int idx = blockIdx.x * 256 + threadIdx.x;   // over B*C*N/4
    const int nq  = idx & (N_ / 4 - 1);
    const int bc  = idx >> 10;                        // b*C + c
    const int b   = bc >> 7;
    const size_t off = (size_t)bc * N_ + nq * 4;

    float4 xv = *(const float4*)(x + off);

    float num[4] = {0, 0, 0, 0}, den[4] = {0, 0, 0, 0};
    #pragma unroll
    for (int q = 0; q < NS; ++q) {
        bf16x4 r = *(const bf16x4*)(pO + (size_t)q * B_ * C_ * N_ + off);
        const float* lp = lG + ((size_t)q * B_ + b) * N_ + nq * 4;
        #pragma unroll
        for (int j = 0; j < 4; ++j) {
            num[j] += (float)r[j];
            den[j] += lp[j];
        }
    }
    float4 ov;
    ov.x = xv.x + num[0] / den[0];
    ov.y = xv.y + num[1] / den[1];
    ov.z = xv.z + num[2] / den[2];
    ov.w = xv.w + num[3] / den[3];
    *(float4*)(out + off) = ov;
}

extern "C" void kernel_launch(void* const* d_in, const int* in_sizes, int n_in,
                              void* d_out, int out_size, void* d_ws, size_t ws_size,
                              hipStream_t stream)
{
    const float* x  = (const float*)d_in[0];
    const float* Wq = (const float*)d_in[1];
    const float* bq = (const float*)d_in[2];
    const float* Wk = (const float*)d_in[3];
    const float* bk = (const float*)d_in[4];
    const float* Wv = (const float*)d_in[5];
    const float* bv = (const float*)d_in[6];
    float* out = (float*)d_out;

    unsigned short* qT = (unsigned short*)d_ws;              // 4 MiB
    char* kQ = (char*)(qT + (size_t)B_ * N_ * C_);           // 4 MiB
    char* vQ = kQ + (size_t)B_ * KB_PER_B;                   // 4 MiB
    unsigned short* pO = (unsigned short*)(vQ + (size_t)B_ * KB_PER_B);

    const size_t slotO = (size_t)B_ * C_ * N_;               // bf16 elems / slot
    const size_t slotL = (size_t)B_ * N_;                    // floats / slot
    const size_t base  = 3ull * B_ * N_ * C_ * 2;
    const size_t need4 = base + 4 * (slotO * 2 + slotL * 4);
    const int nMerge = (B_ * C_ * N_ / 4) / 256;

    proj_kernel<<<384, 256, 0, stream>>>(x, Wq, bq, Wk, bk, Wv, bv, qT, kQ, vQ);

    if (ws_size >= need4) {
        float* lG = (float*)(pO + 4 * slotO);
        attn_kernel<4><<<B_ * (N_ / 128) * 4, 256, 0, stream>>>(qT, kQ, vQ, pO, lG);
        merge_kernel<4><<<nMerge, 256, 0, stream>>>(x, pO, lG, out);
    } else {
        float* lG = (float*)(pO + 2 * slotO);
        attn_kernel<2><<<B_ * (N_ / 128) * 2, 256, 0, stream>>>(qT, kQ, vQ, pO, lG);
        merge_kernel<2><<<nMerge, 256, 0, stream>>>(x, pO, lG, out);
    }
}